// Round 4
// baseline (492.097 us; speedup 1.0000x reference)
//
#include <hip/hip_runtime.h>

// Per-edge cosine similarity, int8-quantized normalized rows (128 B/row = 1 line).
// Round 4: on-device counting sort of edges by src -> CSR-ish order. Edge kernel
// holds the src row in registers across a run (~40 edges/src), so random line
// traffic drops from 2/edge to ~1/edge. Model: L1-MSHR x miss-latency bound at
// ~61 G random lines/s (constant across rounds 1-3).
//
// Pipeline: pack -> memset(cur) -> hist -> scan(in-place) -> scatter -> edge.
// Payload per sorted edge: int2{ (src<<16)|dst, orig_edge_idx } (needs n<65536;
// falls back to round-3 unsorted kernel otherwise).

#define FD 64

__device__ __forceinline__ int q8pack(float v0, float v1, float v2, float v3, float inv) {
    float a0 = fminf(fmaxf(v0 * inv, -127.f), 127.f);
    float a1 = fminf(fmaxf(v1 * inv, -127.f), 127.f);
    float a2 = fminf(fmaxf(v2 * inv, -127.f), 127.f);
    float a3 = fminf(fmaxf(v3 * inv, -127.f), 127.f);
    int q0 = ((int)rintf(a0)) & 0xff;
    int q1 = ((int)rintf(a1)) & 0xff;
    int q2 = ((int)rintf(a2)) & 0xff;
    int q3 = ((int)rintf(a3)) & 0xff;
    return q0 | (q1 << 8) | (q2 << 16) | (q3 << 24);
}

__global__ void pack_kernel(const float4* __restrict__ xd, const float4* __restrict__ hd,
                            const float4* __restrict__ xg, const float4* __restrict__ hg,
                            int2* __restrict__ fd, int2* __restrict__ fg,
                            float* __restrict__ sd, float* __restrict__ sg,
                            int n_d, int n_g)
{
    int tid  = (int)(blockIdx.x * blockDim.x + threadIdx.x);
    int node = tid >> 4;
    int lane = threadIdx.x & 15;
    int total = n_d + n_g;
    if (node >= total) return;

    const float4* x; const float4* h; int2* o; float* s; int n;
    if (node < n_d) { x = xd; h = hd; o = fd; s = sd; n = node; }
    else            { x = xg; h = hg; o = fg; s = sg; n = node - n_d; }

    float4 a = x[(size_t)n * 16 + lane];
    float4 b = h[(size_t)n * 16 + lane];

    float ss = a.x*a.x + a.y*a.y + a.z*a.z + a.w*a.w
             + b.x*b.x + b.y*b.y + b.z*b.z + b.w*b.w;
    #pragma unroll
    for (int m = 8; m >= 1; m >>= 1) ss += __shfl_xor(ss, m);
    float r = rsqrtf(ss);

    a.x *= r; a.y *= r; a.z *= r; a.w *= r;
    b.x *= r; b.y *= r; b.z *= r; b.w *= r;

    float mx = fmaxf(fmaxf(fmaxf(fabsf(a.x), fabsf(a.y)), fmaxf(fabsf(a.z), fabsf(a.w))),
                     fmaxf(fmaxf(fabsf(b.x), fabsf(b.y)), fmaxf(fabsf(b.z), fabsf(b.w))));
    #pragma unroll
    for (int m = 8; m >= 1; m >>= 1) mx = fmaxf(mx, __shfl_xor(mx, m));

    float inv = 127.0f / mx;

    int2 w;
    w.x = q8pack(a.x, a.y, a.z, a.w, inv);
    w.y = q8pack(b.x, b.y, b.z, b.w, inv);
    o[(size_t)n * 16 + lane] = w;

    if (lane == 0) s[n] = mx * (1.0f / 127.0f);
}

__global__ void hist_kernel(const int* __restrict__ src, int* __restrict__ cur, int n_edges)
{
    int i = (int)(blockIdx.x * blockDim.x + threadIdx.x);
    if (i < n_edges) atomicAdd(&cur[src[i]], 1);
}

// In-place exclusive prefix sum over cur[0..nbins). Single block of 1024.
__global__ void scan_kernel(int* __restrict__ cur, int nbins)
{
    __shared__ int psum[1024];
    int t = threadIdx.x;
    int chunk = (nbins + 1023) / 1024;
    int lo = t * chunk;
    int hi = min(lo + chunk, nbins);
    int s = 0;
    for (int i = lo; i < hi; ++i) s += cur[i];
    psum[t] = s;
    __syncthreads();
    if (t == 0) {
        int acc = 0;
        for (int i = 0; i < 1024; ++i) { int v = psum[i]; psum[i] = acc; acc += v; }
    }
    __syncthreads();
    int acc = psum[t];
    for (int i = lo; i < hi; ++i) {
        int v = cur[i];
        cur[i] = acc;
        acc += v;
    }
}

__global__ void scatter_kernel(const int* __restrict__ src, const int* __restrict__ dst,
                               int* __restrict__ cur, int2* __restrict__ sorted, int n_edges)
{
    int i = (int)(blockIdx.x * blockDim.x + threadIdx.x);
    if (i >= n_edges) return;
    int s = src[i];
    int d = dst[i];
    int p = atomicAdd(&cur[s], 1);
    sorted[p] = make_int2((s << 16) | d, i);
}

__device__ __forceinline__ int dot4(int a, int b, int c) {
    return __builtin_amdgcn_sdot4(a, b, c, false);
}

#define CHUNK 32

// 8 lanes per group, one 32-edge chunk of the src-sorted edge array per group.
// src row cached in registers across the run (reloaded only on src change).
__global__ void edge_sorted_kernel(const int4* __restrict__ fd, const int4* __restrict__ fg,
                                   const float* __restrict__ sd, const float* __restrict__ sg,
                                   const int2* __restrict__ sorted,
                                   float* __restrict__ out, int n_edges)
{
    int tid  = (int)(blockIdx.x * blockDim.x + threadIdx.x);
    int lane = threadIdx.x & 7;
    int g    = tid >> 3;
    int base = g * CHUNK;
    if (base >= n_edges) return;
    int lim = min(CHUNK, n_edges - base);

    int s_prev = -1;
    int4 a = make_int4(0, 0, 0, 0);

    #pragma unroll 4
    for (int i = 0; i < lim; ++i) {
        int2 t = sorted[base + i];              // same addr across the 8-lane group
        int s = (int)(((unsigned)t.x) >> 16);
        int d = t.x & 0xffff;
        if (s != s_prev) {                      // ~once per run of ~40 edges
            a = fd[(size_t)s * 8 + lane];
            s_prev = s;
        }
        int4 b = fg[(size_t)d * 8 + lane];      // the one random line per edge
        int acc = dot4(a.x, b.x, dot4(a.y, b.y, dot4(a.z, b.z, dot4(a.w, b.w, 0))));
        acc += __shfl_xor(acc, 4);
        acc += __shfl_xor(acc, 2);
        acc += __shfl_xor(acc, 1);
        if (lane == 0) out[t.y] = (float)acc * sd[s] * sg[d];
    }
}

// Fallback (round-3 unsorted) for the unlikely case n >= 65536.
__global__ void edge_kernel(const int4* __restrict__ fd, const int4* __restrict__ fg,
                            const float* __restrict__ sd, const float* __restrict__ sg,
                            const int* __restrict__ src, const int* __restrict__ dst,
                            float* __restrict__ out, int n_edges)
{
    int tid  = (int)(blockIdx.x * blockDim.x + threadIdx.x);
    int lane = threadIdx.x & 7;
    int e    = tid >> 3;
    if (e >= n_edges) return;
    int s = src[e];
    int d = dst[e];
    int4 a = fd[(size_t)s * 8 + lane];
    int4 b = fg[(size_t)d * 8 + lane];
    int acc = dot4(a.x, b.x, dot4(a.y, b.y, dot4(a.z, b.z, dot4(a.w, b.w, 0))));
    acc += __shfl_xor(acc, 4);
    acc += __shfl_xor(acc, 2);
    acc += __shfl_xor(acc, 1);
    if (lane == 0) out[e] = (float)acc * sd[s] * sg[d];
}

extern "C" void kernel_launch(void* const* d_in, const int* in_sizes, int n_in,
                              void* d_out, int out_size, void* d_ws, size_t ws_size,
                              hipStream_t stream) {
    const float* xd = (const float*)d_in[0];
    const float* hd = (const float*)d_in[1];
    const float* xg = (const float*)d_in[2];
    const float* hg = (const float*)d_in[3];
    const int*  src = (const int*)d_in[4];
    const int*  dst = (const int*)d_in[5];

    int n_d     = in_sizes[0] / FD;
    int n_g     = in_sizes[2] / FD;
    int n_edges = in_sizes[4];

    // ws layout (all offsets 16B-aligned for these sizes):
    //   fd: n_d*128 B | fg: n_g*128 B | sd: n_d*4 | sg: n_g*4 | cur: n_d*4 | sorted: E*8
    char* ws = (char*)d_ws;
    int2*  fd  = (int2*)ws;   ws += (size_t)n_d * 128;
    int2*  fg  = (int2*)ws;   ws += (size_t)n_g * 128;
    float* sd  = (float*)ws;  ws += (size_t)n_d * sizeof(float);
    float* sg  = (float*)ws;  ws += (size_t)n_g * sizeof(float);
    int*   cur = (int*)ws;    ws += (size_t)n_d * sizeof(int);
    int2*  sorted = (int2*)ws;
    float* out = (float*)d_out;

    int total_nodes = n_d + n_g;
    int nb1 = (total_nodes * 16 + 255) / 256;
    pack_kernel<<<nb1, 256, 0, stream>>>((const float4*)xd, (const float4*)hd,
                                         (const float4*)xg, (const float4*)hg,
                                         fd, fg, sd, sg, n_d, n_g);

    if (n_d < 65536 && n_g < 65536) {
        hipMemsetAsync(cur, 0, (size_t)n_d * sizeof(int), stream);

        int nbe = (n_edges + 255) / 256;
        hist_kernel<<<nbe, 256, 0, stream>>>(src, cur, n_edges);
        scan_kernel<<<1, 1024, 0, stream>>>(cur, n_d);
        scatter_kernel<<<nbe, 256, 0, stream>>>(src, dst, cur, sorted, n_edges);

        long long groups = ((long long)n_edges + CHUNK - 1) / CHUNK;
        int nb4 = (int)((groups * 8 + 255) / 256);
        edge_sorted_kernel<<<nb4, 256, 0, stream>>>((const int4*)fd, (const int4*)fg,
                                                    sd, sg, sorted, out, n_edges);
    } else {
        int nb2 = (int)(((long long)n_edges * 8 + 255) / 256);
        edge_kernel<<<nb2, 256, 0, stream>>>((const int4*)fd, (const int4*)fg,
                                             sd, sg, src, dst, out, n_edges);
    }
}

// Round 5
// 160.015 us; speedup vs baseline: 3.0753x; 3.0753x over previous
//
#include <hip/hip_runtime.h>

// Per-edge cosine similarity, int8-quantized normalized rows (128 B/row = 1 line).
// Round 5: revert the sort (scatter write-amplification cost 170us >> savings).
// Round-3 structure + 2-edge ILP unroll per 8-lane group to discriminate
// request-rate-wall vs MSHR-latency models of the ~61 G lines/s gather law.

#define FD 64

__device__ __forceinline__ int q8pack(float v0, float v1, float v2, float v3, float inv) {
    float a0 = fminf(fmaxf(v0 * inv, -127.f), 127.f);
    float a1 = fminf(fmaxf(v1 * inv, -127.f), 127.f);
    float a2 = fminf(fmaxf(v2 * inv, -127.f), 127.f);
    float a3 = fminf(fmaxf(v3 * inv, -127.f), 127.f);
    int q0 = ((int)rintf(a0)) & 0xff;
    int q1 = ((int)rintf(a1)) & 0xff;
    int q2 = ((int)rintf(a2)) & 0xff;
    int q3 = ((int)rintf(a3)) & 0xff;
    return q0 | (q1 << 8) | (q2 << 16) | (q3 << 24);
}

__global__ void pack_kernel(const float4* __restrict__ xd, const float4* __restrict__ hd,
                            const float4* __restrict__ xg, const float4* __restrict__ hg,
                            int2* __restrict__ fd, int2* __restrict__ fg,
                            float* __restrict__ sd, float* __restrict__ sg,
                            int n_d, int n_g)
{
    int tid  = (int)(blockIdx.x * blockDim.x + threadIdx.x);
    int node = tid >> 4;
    int lane = threadIdx.x & 15;
    int total = n_d + n_g;
    if (node >= total) return;

    const float4* x; const float4* h; int2* o; float* s; int n;
    if (node < n_d) { x = xd; h = hd; o = fd; s = sd; n = node; }
    else            { x = xg; h = hg; o = fg; s = sg; n = node - n_d; }

    float4 a = x[(size_t)n * 16 + lane];
    float4 b = h[(size_t)n * 16 + lane];

    float ss = a.x*a.x + a.y*a.y + a.z*a.z + a.w*a.w
             + b.x*b.x + b.y*b.y + b.z*b.z + b.w*b.w;
    #pragma unroll
    for (int m = 8; m >= 1; m >>= 1) ss += __shfl_xor(ss, m);
    float r = rsqrtf(ss);

    a.x *= r; a.y *= r; a.z *= r; a.w *= r;
    b.x *= r; b.y *= r; b.z *= r; b.w *= r;

    float mx = fmaxf(fmaxf(fmaxf(fabsf(a.x), fabsf(a.y)), fmaxf(fabsf(a.z), fabsf(a.w))),
                     fmaxf(fmaxf(fabsf(b.x), fabsf(b.y)), fmaxf(fabsf(b.z), fabsf(b.w))));
    #pragma unroll
    for (int m = 8; m >= 1; m >>= 1) mx = fmaxf(mx, __shfl_xor(mx, m));

    float inv = 127.0f / mx;

    int2 w;
    w.x = q8pack(a.x, a.y, a.z, a.w, inv);
    w.y = q8pack(b.x, b.y, b.z, b.w, inv);
    o[(size_t)n * 16 + lane] = w;

    if (lane == 0) s[n] = mx * (1.0f / 127.0f);
}

__device__ __forceinline__ int dot4(int a, int b, int c) {
    return __builtin_amdgcn_sdot4(a, b, c, false);   // v_dot4_i32_i8
}

// 8 lanes per group, 2 edges per group (ILP: 4 independent row-line loads
// in flight before any use).
__global__ __launch_bounds__(256, 8)
void edge_kernel2(const int4* __restrict__ fd, const int4* __restrict__ fg,
                  const float* __restrict__ sd, const float* __restrict__ sg,
                  const int* __restrict__ src, const int* __restrict__ dst,
                  float* __restrict__ out, int n_edges)
{
    int tid  = (int)(blockIdx.x * blockDim.x + threadIdx.x);
    int lane = threadIdx.x & 7;
    int g    = tid >> 3;
    int e0   = g * 2;
    if (e0 >= n_edges) return;
    int  e1   = min(e0 + 1, n_edges - 1);
    bool has1 = (e0 + 1) < n_edges;

    int s0 = src[e0], d0 = dst[e0];
    int s1 = src[e1], d1 = dst[e1];

    int4 a0 = fd[(size_t)s0 * 8 + lane];
    int4 b0 = fg[(size_t)d0 * 8 + lane];
    int4 a1 = fd[(size_t)s1 * 8 + lane];
    int4 b1 = fg[(size_t)d1 * 8 + lane];

    int acc0 = dot4(a0.x, b0.x, dot4(a0.y, b0.y, dot4(a0.z, b0.z, dot4(a0.w, b0.w, 0))));
    int acc1 = dot4(a1.x, b1.x, dot4(a1.y, b1.y, dot4(a1.z, b1.z, dot4(a1.w, b1.w, 0))));

    acc0 += __shfl_xor(acc0, 4);
    acc0 += __shfl_xor(acc0, 2);
    acc0 += __shfl_xor(acc0, 1);
    acc1 += __shfl_xor(acc1, 4);
    acc1 += __shfl_xor(acc1, 2);
    acc1 += __shfl_xor(acc1, 1);

    if (lane == 0) {
        out[e0] = (float)acc0 * sd[s0] * sg[d0];
        if (has1) out[e1] = (float)acc1 * sd[s1] * sg[d1];
    }
}

extern "C" void kernel_launch(void* const* d_in, const int* in_sizes, int n_in,
                              void* d_out, int out_size, void* d_ws, size_t ws_size,
                              hipStream_t stream) {
    const float* xd = (const float*)d_in[0];
    const float* hd = (const float*)d_in[1];
    const float* xg = (const float*)d_in[2];
    const float* hg = (const float*)d_in[3];
    const int*  src = (const int*)d_in[4];
    const int*  dst = (const int*)d_in[5];

    int n_d     = in_sizes[0] / FD;
    int n_g     = in_sizes[2] / FD;
    int n_edges = in_sizes[4];

    // ws layout: fd rows (n_d*128 B) | fg rows (n_g*128 B) | sd | sg
    char* ws = (char*)d_ws;
    int2*  fd = (int2*)ws;   ws += (size_t)n_d * 128;
    int2*  fg = (int2*)ws;   ws += (size_t)n_g * 128;
    float* sd = (float*)ws;  ws += (size_t)n_d * sizeof(float);
    float* sg = (float*)ws;
    float* out = (float*)d_out;

    int total_nodes = n_d + n_g;
    int nb1 = (total_nodes * 16 + 255) / 256;
    pack_kernel<<<nb1, 256, 0, stream>>>((const float4*)xd, (const float4*)hd,
                                         (const float4*)xg, (const float4*)hg,
                                         fd, fg, sd, sg, n_d, n_g);

    long long groups = ((long long)n_edges + 1) / 2;
    int nb2 = (int)((groups * 8 + 255) / 256);
    edge_kernel2<<<nb2, 256, 0, stream>>>((const int4*)fd, (const int4*)fg,
                                          sd, sg, src, dst, out, n_edges);
}